// Round 19
// baseline (77.537 us; speedup 1.0000x reference)
//
#include <hip/hip_runtime.h>
#include <hip/hip_bf16.h>

// SNN "SynapticChain": B=4, T=24, N=4096, F=32, L=3 (+1 final synaptic layer).
// R19: tile phase made ALL-REGISTER. Each layer computed TRANSPOSED
// (A=weights, B=activations) with a fixed k-slot map k(lg,e)=e<4?lg*4+e:
// 16+lg*4+(e-4) used consistently on both operands (bijection -> contraction
// invariant). Then each MFMA's D output IS the next layer's B-fragment
// layout: lin^T -> T in regs -> hi/lo split -> layer1^T -> prelu -> G in regs
// -> layer2^T -> float4 stores. gbuf deleted (R18's 590K bank conflicts and
// 3 LDS bounce latencies gone); LDS 68->49KB; biases via float4 global loads.
// Tile(tb-1) issued at head of iteration tb (pure reg+MFMA -> scheduler can
// sink it into chain LDS-wait shadows). Chain arithmetic byte-identical (LAW).

namespace {
constexpr int kB = 4;
constexpr int kT = 24;
constexpr int kN = 4096;
constexpr int kF = 32;
constexpr int kNF = kN * kF;

typedef __attribute__((ext_vector_type(8))) short short8v;
typedef __attribute__((ext_vector_type(4))) float float4v;

__device__ __forceinline__ short bfc(float f) {
    return (short)__bfloat16_as_ushort(__float2bfloat16(f));
}
__device__ __forceinline__ float bfc_back(short s) {
    return __bfloat162float(__ushort_as_bfloat16((unsigned short)s));
}
__device__ __forceinline__ float uni(float v) {
    return __int_as_float(__builtin_amdgcn_readfirstlane(__float_as_int(v)));
}
__device__ __forceinline__ constexpr int kmap(int lg, int e) {
    return (e < 4) ? (lg * 4 + e) : (16 + lg * 4 + (e - 4));
}

__global__ __launch_bounds__(512, 2)
void snn_fused(const float* __restrict__ x,
               const float* __restrict__ alphas,
               const float* __restrict__ betas,
               const float* __restrict__ thrs,
               const float* __restrict__ chain_W,
               const float* __restrict__ chain_b,
               const float* __restrict__ lin_W,
               const float* __restrict__ lin_b,
               const float* __restrict__ W1,
               const float* __restrict__ b1,
               const float* __restrict__ prelu_a,
               const float* __restrict__ W2,
               const float* __restrict__ b2,
               float* __restrict__ out)
{
    const int tid  = threadIdx.x;
    const int lane = tid & 63;
    const int half = lane >> 5;             // chain: row-half
    const int l    = lane & 31;             // chain: feature
    const int wid  = tid >> 6;              // 0..7
    const int l16  = lane & 15;             // mfma row/col
    const int lg   = lane >> 4;             // 0..3

    const int base = blockIdx.x * 32 + wid * 4;   // wave's 4 bn-rows
    const int rowA = base + half;
    const int rowB = rowA + 2;
    const int bA   = rowA >> 12;
    const int nA   = rowA & (kN - 1);
    const int bB   = rowB >> 12;
    const int nB   = rowB & (kN - 1);
    const int bq   = base >> 12;
    const int n0   = base & (kN - 1);

    __shared__ float    lut[3][8][16][32];  // 48 KB (mats 0..2)
    __shared__ unsigned mlds[8][2][4][4];   // 1 KB, double-buffered masks

    // ---- LUT init: byte-identical arithmetic to R12/R17/R18
#pragma unroll
    for (int c = 0; c < 2; ++c) {
        const int idx = tid + c * 512;
        if (idx < 768) {
            const int mat = idx >> 8;
            const int g   = (idx >> 5) & 7;
            const int jj  = idx & 31;
            const float* wsrc = chain_W + ((mat * kF + jj) * kF + g * 4);
            const float4 w = *reinterpret_cast<const float4*>(wsrc);
            const float bias = (g == 0) ? chain_b[mat * kF + jj] : 0.0f;
            float s[16];
            s[0]  = 0.0f;
            s[1]  = w.x;         s[2]  = w.y;         s[3]  = w.x + w.y;
            s[4]  = w.z;         s[5]  = w.x + w.z;   s[6]  = w.y + w.z;
            s[7]  = s[3] + w.z;  s[8]  = w.w;         s[9]  = w.x + w.w;
            s[10] = w.y + w.w;   s[11] = s[3] + w.w;  s[12] = w.z + w.w;
            s[13] = s[5] + w.w;  s[14] = s[6] + w.w;  s[15] = s[7] + w.w;
#pragma unroll
            for (int nb = 0; nb < 16; ++nb) lut[mat][g][nb][jj] = s[nb] + bias;
        }
    }
    __syncthreads();

    // ---- uniform scalars -> SGPR
    float al[4], be[4], th[4];
#pragma unroll
    for (int i = 0; i < 4; ++i) {
        al[i] = uni(fminf(fmaxf(alphas[i], 0.0f), 1.0f));
        be[i] = uni(fminf(fmaxf(betas[i],  0.0f), 1.0f));
        th[i] = uni(thrs[i]);
    }
    const float pa = uni(prelu_a[0]);

    // ---- weight fragments in kmap order (A-side of transposed layers)
    short8v lf[2][2];                       // lin_W rows, double-split
#pragma unroll
    for (int c = 0; c < 2; ++c) {
#pragma unroll
        for (int e = 0; e < 8; ++e) {
            const float w  = lin_W[(c * 16 + l16) * 32 + kmap(lg, e)];
            const short s0 = bfc(w);
            lf[c][0][e] = s0;
            lf[c][1][e] = bfc(w - bfc_back(s0));
        }
    }
    short8v w1f[4];                         // W1 rows, bf16
#pragma unroll
    for (int q = 0; q < 4; ++q)
#pragma unroll
        for (int e = 0; e < 8; ++e)
            w1f[q][e] = bfc(W1[(q * 16 + l16) * 32 + kmap(lg, e)]);
    short8v w2f[2][2];                      // W2 rows, bf16, [oq][kb]
#pragma unroll
    for (int oq = 0; oq < 2; ++oq)
#pragma unroll
        for (int kb = 0; kb < 2; ++kb)
#pragma unroll
            for (int e = 0; e < 8; ++e)
                w2f[oq][kb][e] = bfc(W2[(oq * 16 + l16) * 64 + kb * 32 + kmap(lg, e)]);

    // ---- chain state (byte-identical recurrence)
    float synA[4] = {0.f, 0.f, 0.f, 0.f};
    float memA[4] = {0.f, 0.f, 0.f, 0.f};
    float synB[4] = {0.f, 0.f, 0.f, 0.f};
    float memB[4] = {0.f, 0.f, 0.f, 0.f};

    const float* xpA = x + (size_t)(bA * kT * kN + nA) * kF + l;
    const float* xpB = x + (size_t)(bB * kT * kN + nB) * kF + l;

    float xvA = xpA[0];
    float xvB = xpB[0];

    // ---- all-register tile for time-block tbp (masks already in mlds)
    auto tile = [&](int tbp) {
        const unsigned m = mlds[wid][tbp & 1][l16 >> 2][l16 & 3];
        short8v aspk;
#pragma unroll
        for (int e = 0; e < 8; ++e)
            aspk[e] = ((m >> kmap(lg, e)) & 1u) ? (short)0x3F80 : (short)0;

        // lin_out^T: T[n][feat] ; lane gets T[l16][c*16+lg*4+r]
        const float4 lb0 = *reinterpret_cast<const float4*>(lin_b + lg * 4);
        const float4 lb1 = *reinterpret_cast<const float4*>(lin_b + 16 + lg * 4);
        float4v t0 = {lb0.x, lb0.y, lb0.z, lb0.w};
        float4v t1 = {lb1.x, lb1.y, lb1.z, lb1.w};
        t0 = __builtin_amdgcn_mfma_f32_16x16x32_bf16(lf[0][0], aspk, t0, 0, 0, 0);
        t0 = __builtin_amdgcn_mfma_f32_16x16x32_bf16(lf[0][1], aspk, t0, 0, 0, 0);
        t1 = __builtin_amdgcn_mfma_f32_16x16x32_bf16(lf[1][0], aspk, t1, 0, 0, 0);
        t1 = __builtin_amdgcn_mfma_f32_16x16x32_bf16(lf[1][1], aspk, t1, 0, 0, 0);

        // T -> hi/lo B-fragments (slot e<4 from t0[e], e>=4 from t1[e-4])
        short8v thi, tlo;
#pragma unroll
        for (int e = 0; e < 4; ++e) {
            const short h0 = bfc(t0[e]);
            thi[e] = h0; tlo[e] = bfc(t0[e] - bfc_back(h0));
            const short h1 = bfc(t1[e]);
            thi[4 + e] = h1; tlo[4 + e] = bfc(t1[e] - bfc_back(h1));
        }

        // layer1^T + prelu: G[l16][q*16+lg*4+r] -> g[q*4+r]
        float g[16];
#pragma unroll
        for (int q = 0; q < 4; ++q) {
            const float4 b14 = *reinterpret_cast<const float4*>(b1 + q * 16 + lg * 4);
            float4v c = {b14.x, b14.y, b14.z, b14.w};
            c = __builtin_amdgcn_mfma_f32_16x16x32_bf16(w1f[q], thi, c, 0, 0, 0);
            c = __builtin_amdgcn_mfma_f32_16x16x32_bf16(w1f[q], tlo, c, 0, 0, 0);
#pragma unroll
            for (int r = 0; r < 4; ++r) {
                const float v = c[r];
                g[q * 4 + r] = (v > 0.0f) ? v : pa * v;
            }
        }

        // G -> hi/lo B-fragments per kb (slot e <-> g[kb*8+e])
        short8v gh[2], gl[2];
#pragma unroll
        for (int kb = 0; kb < 2; ++kb)
#pragma unroll
            for (int e = 0; e < 8; ++e) {
                const float v = g[kb * 8 + e];
                const short h0 = bfc(v);
                gh[kb][e] = h0;
                gl[kb][e] = bfc(v - bfc_back(h0));
            }

        // layer2^T + store: lane holds out[l16][oq*16+lg*4+r] -> float4
        const size_t rowbase =
            ((size_t)(bq * kT + tbp * 4 + (l16 >> 2)) * kN + (n0 + (l16 & 3))) * kF;
#pragma unroll
        for (int oq = 0; oq < 2; ++oq) {
            const float4 b24 = *reinterpret_cast<const float4*>(b2 + oq * 16 + lg * 4);
            float4v o = {b24.x, b24.y, b24.z, b24.w};
            o = __builtin_amdgcn_mfma_f32_16x16x32_bf16(w2f[oq][0], gh[0], o, 0, 0, 0);
            o = __builtin_amdgcn_mfma_f32_16x16x32_bf16(w2f[oq][0], gl[0], o, 0, 0, 0);
            o = __builtin_amdgcn_mfma_f32_16x16x32_bf16(w2f[oq][1], gh[1], o, 0, 0, 0);
            o = __builtin_amdgcn_mfma_f32_16x16x32_bf16(w2f[oq][1], gl[1], o, 0, 0, 0);
            float4 st = {o[0], o[1], o[2], o[3]};
            *reinterpret_cast<float4*>(out + rowbase + oq * 16 + lg * 4) = st;
        }
    };

    for (int tb = 0; tb < 6; ++tb) {
        if (tb > 0) tile(tb - 1);           // pure reg+MFMA: overlaps chain

        // ======== 4 chain steps (byte-identical recurrent arithmetic) ======
        for (int tt = 0; tt < 4; ++tt) {
            const int t = tb * 4 + tt;
            float xnA = 0.0f, xnB = 0.0f;
            if (t + 1 < kT) {
                xnA = xpA[(size_t)(t + 1) * kNF];
                xnB = xpB[(size_t)(t + 1) * kNF];
            }

            float hA = xvA, hB = xvB;

#pragma unroll
            for (int i = 0; i < 4; ++i) {
                const float rstA = ((memA[i] - th[i]) > 0.0f) ? 1.0f : 0.0f;
                const float rstB = ((memB[i] - th[i]) > 0.0f) ? 1.0f : 0.0f;
                synA[i] = al[i] * synA[i] + hA;
                synB[i] = al[i] * synB[i] + hB;
                memA[i] = be[i] * memA[i] + synA[i] - rstA * th[i];
                memB[i] = be[i] * memB[i] + synB[i] - rstB * th[i];
                const bool spA = (memA[i] - th[i]) > 0.0f;
                const bool spB = (memB[i] - th[i]) > 0.0f;

                const unsigned long long a64 = __ballot(spA);
                const unsigned long long b64 = __ballot(spB);
                const unsigned mA = half ? (unsigned)(a64 >> 32) : (unsigned)a64;
                const unsigned mB = half ? (unsigned)(b64 >> 32) : (unsigned)b64;

                if (i < 3) {
                    float vA[8], vB[8];
#pragma unroll
                    for (int g2 = 0; g2 < 8; ++g2) {
                        vA[g2] = lut[i][g2][(mA >> (4 * g2)) & 15u][l];
                        vB[g2] = lut[i][g2][(mB >> (4 * g2)) & 15u][l];
                    }
                    hA = ((vA[0] + vA[1]) + (vA[2] + vA[3]))
                       + ((vA[4] + vA[5]) + (vA[6] + vA[7]));
                    hB = ((vB[0] + vB[1]) + (vB[2] + vB[3]))
                       + ((vB[4] + vB[5]) + (vB[6] + vB[7]));
                } else if (l == 0) {
                    mlds[wid][tb & 1][tt][half]     = mA;   // bn = base+half
                    mlds[wid][tb & 1][tt][2 + half] = mB;   // bn = base+2+half
                }
            }

            xvA = xnA;
            xvB = xnB;
        }
    }
    tile(5);
}
} // namespace

extern "C" void kernel_launch(void* const* d_in, const int* in_sizes, int n_in,
                              void* d_out, int out_size, void* d_ws, size_t ws_size,
                              hipStream_t stream) {
    const float* x        = (const float*)d_in[0];
    const float* alphas   = (const float*)d_in[1];
    const float* betas    = (const float*)d_in[2];
    const float* thrs     = (const float*)d_in[3];
    const float* chain_W  = (const float*)d_in[4];
    const float* chain_b  = (const float*)d_in[5];
    const float* lin_W    = (const float*)d_in[6];
    const float* lin_b    = (const float*)d_in[7];
    const float* W1       = (const float*)d_in[8];
    const float* b1       = (const float*)d_in[9];
    const float* prelu_a  = (const float*)d_in[10];
    const float* W2       = (const float*)d_in[11];
    const float* b2       = (const float*)d_in[12];
    float* out            = (float*)d_out;

    // 512 blocks * 8 waves * 4 bn-rows = 16384 rows; fused chain+tile
    hipLaunchKernelGGL(snn_fused, dim3(512), dim3(512), 0, stream,
                       x, alphas, betas, thrs, chain_W, chain_b, lin_W, lin_b,
                       W1, b1, prelu_a, W2, b2, out);
}

// Round 20
// 60.652 us; speedup vs baseline: 1.2784x; 1.2784x over previous
//
#include <hip/hip_runtime.h>
#include <hip/hip_bf16.h>

// SNN "SynapticChain": B=4, T=24, N=4096, F=32, L=3 (+1 final synaptic layer).
// R20: chain is LDS-ISSUE-bound (12 ds_read_b32/row-t = ~44.6us/CU of the
// 51.5us). Restructure: wave = 8 rows x 8 feature-quads; LUT permuted to
// lutQ[mat][g][nib][q][4] (features q,q+8,q+16,q+24 contiguous) -> one
// ds_read_b128 per (row,layer,group)-set = 3 instr/row-t (4x fewer).
// Mask assembly integer-exact: 4 ballots -> m32 = fld0|fld1<<8|fld2<<16|
// fld3<<24, bit j == feature j, so the PROVEN nibble extraction and the
// PROVEN per-feature f32 add tree + state-update expressions are unchanged
// (same source, same order -> same bits; only layout + integer plumbing new).
// snn_mlp: R17 verbatim (mask -> lin_out -> layer1/2 MFMA, ~21us proven).

namespace {
constexpr int kB = 4;
constexpr int kT = 24;
constexpr int kN = 4096;
constexpr int kF = 32;
constexpr int kNF = kN * kF;

typedef __attribute__((ext_vector_type(8))) short short8v;
typedef __attribute__((ext_vector_type(4))) float float4v;

__device__ __forceinline__ short bfc(float f) {
    return (short)__bfloat16_as_ushort(__float2bfloat16(f));
}
__device__ __forceinline__ float bfc_back(short s) {
    return __bfloat162float(__ushort_as_bfloat16((unsigned short)s));
}

// activations: hi/lo bf16 split (proven R15)
__device__ __forceinline__ void cvt_hilo(const float* v, short8v& hi, short8v& lo) {
#pragma unroll
    for (int e = 0; e < 8; ++e) {
        const short h = bfc(v[e]);
        hi[e] = h;
        lo[e] = bfc(v[e] - bfc_back(h));
    }
}

__device__ __forceinline__ short8v load8w(const float* p) {
    short8v r;
#pragma unroll
    for (int e = 0; e < 8; ++e) r[e] = bfc(p[e]);
    return r;
}

// ---------------- Kernel 1: recurrent chain -> spike masks ----------------
__global__ __launch_bounds__(512, 2)
void snn_chain(const float* __restrict__ x,
               const float* __restrict__ alphas,
               const float* __restrict__ betas,
               const float* __restrict__ thrs,
               const float* __restrict__ chain_W,
               const float* __restrict__ chain_b,
               float* __restrict__ out)
{
    const int tid  = threadIdx.x;
    const int lane = tid & 63;
    const int wid  = tid >> 6;              // 0..7
    const int r    = lane >> 3;             // row within wave 0..7
    const int q    = lane & 7;              // feature quad id 0..7
    const int row  = (blockIdx.x * 8 + wid) * 8 + r;
    const int b    = row >> 12;
    const int n    = row & (kN - 1);

    // permuted nibble LUT: [mat][g][nib][q][slot]; slot s = feature q+8s
    __shared__ float lutQ[3][8][16][8][4];  // 48 KB

    // ---- LUT build: same s-table arithmetic as R12/R17; writes permuted
#pragma unroll
    for (int c = 0; c < 2; ++c) {
        const int idx = tid + c * 512;
        if (idx < 768) {
            const int mat = idx >> 8;
            const int g   = (idx >> 5) & 7;
            const int jj  = idx & 31;
            const float* wsrc = chain_W + ((mat * kF + jj) * kF + g * 4);
            const float4 w = *reinterpret_cast<const float4*>(wsrc);
            const float bias = (g == 0) ? chain_b[mat * kF + jj] : 0.0f;
            float s[16];
            s[0]  = 0.0f;
            s[1]  = w.x;         s[2]  = w.y;         s[3]  = w.x + w.y;
            s[4]  = w.z;         s[5]  = w.x + w.z;   s[6]  = w.y + w.z;
            s[7]  = s[3] + w.z;  s[8]  = w.w;         s[9]  = w.x + w.w;
            s[10] = w.y + w.w;   s[11] = s[3] + w.w;  s[12] = w.z + w.w;
            s[13] = s[5] + w.w;  s[14] = s[6] + w.w;  s[15] = s[7] + w.w;
#pragma unroll
            for (int nb = 0; nb < 16; ++nb)
                lutQ[mat][g][nb][jj & 7][jj >> 3] = s[nb] + bias;
        }
    }
    __syncthreads();

    float al[4], be[4], th[4];
#pragma unroll
    for (int i = 0; i < 4; ++i) {
        al[i] = fminf(fmaxf(alphas[i], 0.0f), 1.0f);
        be[i] = fminf(fmaxf(betas[i],  0.0f), 1.0f);
        th[i] = thrs[i];
    }

    float syn[4][4], mem[4][4];             // [layer][slot]
#pragma unroll
    for (int i = 0; i < 4; ++i)
#pragma unroll
        for (int s = 0; s < 4; ++s) { syn[i][s] = 0.0f; mem[i][s] = 0.0f; }

    const float* xp = x   + (size_t)(b * kT * kN + n) * kF + q;
    float*       op = out + (size_t)(b * kT * kN + n) * kF;

    float xv[4];
#pragma unroll
    for (int s = 0; s < 4; ++s) xv[s] = xp[8 * s];

    for (int t = 0; t < kT; ++t) {
        float xn[4] = {0.f, 0.f, 0.f, 0.f};
        if (t + 1 < kT) {
#pragma unroll
            for (int s = 0; s < 4; ++s) xn[s] = xp[(size_t)(t + 1) * kNF + 8 * s];
        }

        float hh[4];
#pragma unroll
        for (int s = 0; s < 4; ++s) hh[s] = xv[s];

#pragma unroll
        for (int i = 0; i < 4; ++i) {
            // state update: same source expressions per feature as R17
            bool sp[4];
#pragma unroll
            for (int s = 0; s < 4; ++s) {
                const float rst = ((mem[i][s] - th[i]) > 0.0f) ? 1.0f : 0.0f;
                syn[i][s] = al[i] * syn[i][s] + hh[s];
                mem[i][s] = be[i] * mem[i][s] + syn[i][s] - rst * th[i];
                sp[s] = (mem[i][s] - th[i]) > 0.0f;
            }
            unsigned long long bal0 = __ballot(sp[0]);
            unsigned long long bal1 = __ballot(sp[1]);
            unsigned long long bal2 = __ballot(sp[2]);
            unsigned long long bal3 = __ballot(sp[3]);
            const unsigned f0 = (unsigned)((bal0 >> (r * 8)) & 0xFFull);
            const unsigned f1 = (unsigned)((bal1 >> (r * 8)) & 0xFFull);
            const unsigned f2 = (unsigned)((bal2 >> (r * 8)) & 0xFFull);
            const unsigned f3 = (unsigned)((bal3 >> (r * 8)) & 0xFFull);
            // bit j of m32 == spike of feature j  (j = q + 8s)
            const unsigned m32 = f0 | (f1 << 8) | (f2 << 16) | (f3 << 24);

            if (i < 3) {
                float4v vv[8];
#pragma unroll
                for (int g = 0; g < 8; ++g) {
                    const unsigned nib = (m32 >> (4 * g)) & 15u;
                    vv[g] = *reinterpret_cast<const float4v*>(&lutQ[i][g][nib][q][0]);
                }
                // identical per-feature add tree as proven path
#pragma unroll
                for (int s = 0; s < 4; ++s)
                    hh[s] = ((vv[0][s] + vv[1][s]) + (vv[2][s] + vv[3][s]))
                          + ((vv[4][s] + vv[5][s]) + (vv[6][s] + vv[7][s]));
            } else if (q == 0) {
                // layer-3 spike mask -> word 0 of the output row
                *reinterpret_cast<unsigned*>(op + (size_t)t * kNF) = m32;
            }
        }

#pragma unroll
        for (int s = 0; s < 4; ++s) xv[s] = xn[s];
    }
}

// ------- Kernel 2: MFMA lin_out + MLP from spike masks (R17 verbatim) -----
__global__ __launch_bounds__(512, 2)
void snn_mlp(const float* __restrict__ lin_W,
             const float* __restrict__ lin_b,
             const float* __restrict__ W1,
             const float* __restrict__ b1,
             const float* __restrict__ prelu_a,
             const float* __restrict__ W2,
             const float* __restrict__ b2,
             float* out)
{
    const int tid   = threadIdx.x;
    const int lane  = tid & 63;
    const int wid   = tid >> 6;             // wave in block, 0..7
    const int l16   = lane & 15;
    const int lg    = lane >> 4;            // 0..3
    const int gwave = (blockIdx.x * 512 + tid) >> 6;   // 0..8191

    __shared__ float gbuf[8][16][68];       // 34.8 KB

    const float pa = prelu_a[0];

    // lin_out B-fragments: double-split bf16 (spikes exact {0,1}; err ~2e-5)
    short8v lf[2][2];                       // [col][split]
#pragma unroll
    for (int c = 0; c < 2; ++c) {
#pragma unroll
        for (int e = 0; e < 8; ++e) {
            const float w  = lin_W[(c * 16 + l16) * 32 + lg * 8 + e];
            const short s0 = bfc(w);
            const short s1 = bfc(w - bfc_back(s0));
            lf[c][0][e] = s0;
            lf[c][1][e] = s1;
        }
    }
    float lbv[2];
#pragma unroll
    for (int c = 0; c < 2; ++c) lbv[c] = lin_b[c * 16 + l16];

    short8v w1f[4], w2f[2][2];
#pragma unroll
    for (int c0 = 0; c0 < 4; ++c0)
        w1f[c0] = load8w(W1 + (c0 * 16 + l16) * 32 + lg * 8);
#pragma unroll
    for (int c2 = 0; c2 < 2; ++c2)
#pragma unroll
        for (int kb = 0; kb < 2; ++kb)
            w2f[c2][kb] = load8w(W2 + (c2 * 16 + l16) * 64 + kb * 32 + lg * 8);

    float b1v[4], b2v[2];
#pragma unroll
    for (int c0 = 0; c0 < 4; ++c0) b1v[c0] = b1[c0 * 16 + l16];
#pragma unroll
    for (int c2 = 0; c2 < 2; ++c2) b2v[c2] = b2[c2 * 16 + l16];

    for (int i = 0; i < 3; ++i) {
        const int tile = gwave * 3 + i;
        const int r0   = tile * 16;

        const unsigned m =
            *reinterpret_cast<const unsigned*>(out + (size_t)(r0 + l16) * kF);
        short8v aspk;
#pragma unroll
        for (int e = 0; e < 8; ++e)
            aspk[e] = ((m >> (lg * 8 + e)) & 1u) ? (short)0x3F80 : (short)0;

        float4v t0 = {lbv[0], lbv[0], lbv[0], lbv[0]};
        float4v t1 = {lbv[1], lbv[1], lbv[1], lbv[1]};
        t0 = __builtin_amdgcn_mfma_f32_16x16x32_bf16(aspk, lf[0][0], t0, 0, 0, 0);
        t0 = __builtin_amdgcn_mfma_f32_16x16x32_bf16(aspk, lf[0][1], t0, 0, 0, 0);
        t1 = __builtin_amdgcn_mfma_f32_16x16x32_bf16(aspk, lf[1][0], t1, 0, 0, 0);
        t1 = __builtin_amdgcn_mfma_f32_16x16x32_bf16(aspk, lf[1][1], t1, 0, 0, 0);

#pragma unroll
        for (int rr = 0; rr < 4; ++rr) {
            gbuf[wid][lg * 4 + rr][l16]      = t0[rr];
            gbuf[wid][lg * 4 + rr][16 + l16] = t1[rr];
        }
        float tv[8];
        const float* pt = &gbuf[wid][l16][lg * 8];
        *reinterpret_cast<float4*>(tv)     = *reinterpret_cast<const float4*>(pt);
        *reinterpret_cast<float4*>(tv + 4) = *reinterpret_cast<const float4*>(pt + 4);
        short8v ahi, alo;
        cvt_hilo(tv, ahi, alo);

        float4v acc[4];
#pragma unroll
        for (int c0 = 0; c0 < 4; ++c0) {
            float4v c = {b1v[c0], b1v[c0], b1v[c0], b1v[c0]};
            c = __builtin_amdgcn_mfma_f32_16x16x32_bf16(ahi, w1f[c0], c, 0, 0, 0);
            c = __builtin_amdgcn_mfma_f32_16x16x32_bf16(alo, w1f[c0], c, 0, 0, 0);
            acc[c0] = c;
        }

#pragma unroll
        for (int c0 = 0; c0 < 4; ++c0) {
#pragma unroll
            for (int rr = 0; rr < 4; ++rr) {
                float v = acc[c0][rr];
                v = (v > 0.0f) ? v : pa * v;
                gbuf[wid][lg * 4 + rr][c0 * 16 + l16] = v;
            }
        }

        float4v o[2];
#pragma unroll
        for (int c2 = 0; c2 < 2; ++c2)
            o[c2] = float4v{b2v[c2], b2v[c2], b2v[c2], b2v[c2]};
#pragma unroll
        for (int kb = 0; kb < 2; ++kb) {
            float gv[8];
            const float* pg = &gbuf[wid][l16][kb * 32 + lg * 8];
            *reinterpret_cast<float4*>(gv)     = *reinterpret_cast<const float4*>(pg);
            *reinterpret_cast<float4*>(gv + 4) = *reinterpret_cast<const float4*>(pg + 4);
            short8v ghi, glo;
            cvt_hilo(gv, ghi, glo);
#pragma unroll
            for (int c2 = 0; c2 < 2; ++c2) {
                o[c2] = __builtin_amdgcn_mfma_f32_16x16x32_bf16(ghi, w2f[c2][kb], o[c2], 0, 0, 0);
                o[c2] = __builtin_amdgcn_mfma_f32_16x16x32_bf16(glo, w2f[c2][kb], o[c2], 0, 0, 0);
            }
        }

#pragma unroll
        for (int c2 = 0; c2 < 2; ++c2)
#pragma unroll
            for (int rr = 0; rr < 4; ++rr)
                out[(size_t)(r0 + lg * 4 + rr) * kF + c2 * 16 + l16] = o[c2][rr];
    }
}
} // namespace

extern "C" void kernel_launch(void* const* d_in, const int* in_sizes, int n_in,
                              void* d_out, int out_size, void* d_ws, size_t ws_size,
                              hipStream_t stream) {
    const float* x        = (const float*)d_in[0];
    const float* alphas   = (const float*)d_in[1];
    const float* betas    = (const float*)d_in[2];
    const float* thrs     = (const float*)d_in[3];
    const float* chain_W  = (const float*)d_in[4];
    const float* chain_b  = (const float*)d_in[5];
    const float* lin_W    = (const float*)d_in[6];
    const float* lin_b    = (const float*)d_in[7];
    const float* W1       = (const float*)d_in[8];
    const float* b1       = (const float*)d_in[9];
    const float* prelu_a  = (const float*)d_in[10];
    const float* W2       = (const float*)d_in[11];
    const float* b2       = (const float*)d_in[12];
    float* out            = (float*)d_out;

    // K1: 16384 rows / (8 waves * 8 rows) = 256 blocks; writes masks
    hipLaunchKernelGGL(snn_chain, dim3(256), dim3(512), 0, stream,
                       x, alphas, betas, thrs, chain_W, chain_b, out);
    // K2: 24576 tiles of 16 rows; 1024 blocks * 8 waves * 3 tiles (exact)
    hipLaunchKernelGGL(snn_mlp, dim3(1024), dim3(512), 0, stream,
                       lin_W, lin_b, W1, b1, prelu_a, W2, b2, out);
}

// Round 21
// 50.168 us; speedup vs baseline: 1.5455x; 1.2090x over previous
//
#include <hip/hip_runtime.h>
#include <hip/hip_bf16.h>

// SNN "SynapticChain": B=4, T=24, N=4096, F=32, L=3 (+1 final synaptic layer).
// R21: FUSE R20-chain + R17-tile. Chain (8 rows/wave, lutQ b128, arithmetic
// BYTE-IDENTICAL to R20 -> bit-identical spikes) emits layer-3 masks to a
// 512B per-wave LDS buffer; after every 2 t-steps the wave's 8 rows x 2 t
// form one 16-row MFMA tile = R17's proven body (lin double-split -> gbuf
// bounce -> layer1/prelu/layer2 hi/lo), with stores remapped to (t,n).
// R18's fusion failed because chain LDS was saturated (44/51us); now LDS is
// ~23/38us -> tile MFMA/VMEM fills the latency bubbles. VGPR diet: al/be/th
// -> SGPR; all 12 weight fragments in LDS (wfrag, 12KB, R16 pattern) => -48
// VGPR. LDS 94.5KB -> 1 block/CU (= current occupancy). Deleted: 2nd launch,
// mask HBM round-trip, cross-XCD mask-miss latency, per-mlp-wave W loads.

namespace {
constexpr int kB = 4;
constexpr int kT = 24;
constexpr int kN = 4096;
constexpr int kF = 32;
constexpr int kNF = kN * kF;

typedef __attribute__((ext_vector_type(8))) short short8v;
typedef __attribute__((ext_vector_type(4))) float float4v;

__device__ __forceinline__ short bfc(float f) {
    return (short)__bfloat16_as_ushort(__float2bfloat16(f));
}
__device__ __forceinline__ float bfc_back(short s) {
    return __bfloat162float(__ushort_as_bfloat16((unsigned short)s));
}
__device__ __forceinline__ float uni(float v) {
    return __int_as_float(__builtin_amdgcn_readfirstlane(__float_as_int(v)));
}

// activations: hi/lo bf16 split (proven R15)
__device__ __forceinline__ void cvt_hilo(const float* v, short8v& hi, short8v& lo) {
#pragma unroll
    for (int e = 0; e < 8; ++e) {
        const short h = bfc(v[e]);
        hi[e] = h;
        lo[e] = bfc(v[e] - bfc_back(h));
    }
}

__global__ __launch_bounds__(512, 2)
void snn_fused(const float* __restrict__ x,
               const float* __restrict__ alphas,
               const float* __restrict__ betas,
               const float* __restrict__ thrs,
               const float* __restrict__ chain_W,
               const float* __restrict__ chain_b,
               const float* __restrict__ lin_W,
               const float* __restrict__ lin_b,
               const float* __restrict__ W1,
               const float* __restrict__ b1,
               const float* __restrict__ prelu_a,
               const float* __restrict__ W2,
               const float* __restrict__ b2,
               float* __restrict__ out)
{
    const int tid  = threadIdx.x;
    const int lane = tid & 63;
    const int wid  = tid >> 6;              // 0..7
    const int r    = lane >> 3;             // chain: row within wave 0..7
    const int q    = lane & 7;              // chain: feature quad id 0..7
    const int l16  = lane & 15;             // mfma row/col
    const int lg   = lane >> 4;             // mfma 0..3

    const int base = (blockIdx.x * 8 + wid) * 8;    // wave's 8 bn-rows
    const int row  = base + r;
    const int b    = row >> 12;
    const int n    = row & (kN - 1);
    const int bq   = base >> 12;
    const int n0   = base & (kN - 1);

    __shared__ float    lutQ[3][8][16][8][4];  // 48 KB (chain, R20 layout)
    __shared__ float    gbuf[8][16][68];       // 34.8 KB (tile bounce, R17)
    __shared__ short8v  wfrag[12][64];         // 12 KB  (tile weight frags)
    __shared__ unsigned mlds[8][2][8];         // 512 B  (masks [tt][r])

    // ---- LUT build: same arithmetic as R12/R17/R20, permuted layout
#pragma unroll
    for (int c = 0; c < 2; ++c) {
        const int idx = tid + c * 512;
        if (idx < 768) {
            const int mat = idx >> 8;
            const int g   = (idx >> 5) & 7;
            const int jj  = idx & 31;
            const float* wsrc = chain_W + ((mat * kF + jj) * kF + g * 4);
            const float4 w = *reinterpret_cast<const float4*>(wsrc);
            const float bias = (g == 0) ? chain_b[mat * kF + jj] : 0.0f;
            float s[16];
            s[0]  = 0.0f;
            s[1]  = w.x;         s[2]  = w.y;         s[3]  = w.x + w.y;
            s[4]  = w.z;         s[5]  = w.x + w.z;   s[6]  = w.y + w.z;
            s[7]  = s[3] + w.z;  s[8]  = w.w;         s[9]  = w.x + w.w;
            s[10] = w.y + w.w;   s[11] = s[3] + w.w;  s[12] = w.z + w.w;
            s[13] = s[5] + w.w;  s[14] = s[6] + w.w;  s[15] = s[7] + w.w;
#pragma unroll
            for (int nb = 0; nb < 16; ++nb)
                lutQ[mat][g][nb][jj & 7][jj >> 3] = s[nb] + bias;
        }
    }

    // ---- tile weight fragments -> LDS (values identical to R17's regs)
    // frag 0..3: lin_W col c=f>>1, split s=f&1 (double-split)
    // frag 4..7: W1 row-block c0=f-4 (bf16)     frag 8..11: W2 [c2][kb]
#pragma unroll
    for (int c = 0; c < 2; ++c) {
        const int idx = tid + c * 512;
        if (idx < 768) {
            const int f     = idx >> 6;
            const int lane2 = idx & 63;
            const int l16b  = lane2 & 15, lgb = lane2 >> 4;
            short8v fr;
            if (f < 4) {
                const int cc = f >> 1, sp = f & 1;
#pragma unroll
                for (int e = 0; e < 8; ++e) {
                    const float w  = lin_W[(cc * 16 + l16b) * 32 + lgb * 8 + e];
                    const short s0 = bfc(w);
                    fr[e] = sp ? bfc(w - bfc_back(s0)) : s0;
                }
            } else if (f < 8) {
                const int c0 = f - 4;
#pragma unroll
                for (int e = 0; e < 8; ++e)
                    fr[e] = bfc(W1[(c0 * 16 + l16b) * 32 + lgb * 8 + e]);
            } else {
                const int c2 = (f - 8) >> 1, kb = (f - 8) & 1;
#pragma unroll
                for (int e = 0; e < 8; ++e)
                    fr[e] = bfc(W2[(c2 * 16 + l16b) * 64 + kb * 32 + lgb * 8 + e]);
            }
            wfrag[f][lane2] = fr;
        }
    }
    __syncthreads();

    // ---- uniform scalars -> SGPR (value-identical; VGPR relief)
    float al[4], be[4], th[4];
#pragma unroll
    for (int i = 0; i < 4; ++i) {
        al[i] = uni(fminf(fmaxf(alphas[i], 0.0f), 1.0f));
        be[i] = uni(fminf(fmaxf(betas[i],  0.0f), 1.0f));
        th[i] = uni(thrs[i]);
    }
    const float pa = uni(prelu_a[0]);

    float lbv[2], b1v[4], b2v[2];
#pragma unroll
    for (int c = 0; c < 2; ++c)  lbv[c]  = lin_b[c * 16 + l16];
#pragma unroll
    for (int c0 = 0; c0 < 4; ++c0) b1v[c0] = b1[c0 * 16 + l16];
#pragma unroll
    for (int c2 = 0; c2 < 2; ++c2) b2v[c2] = b2[c2 * 16 + l16];

    // ---- chain state (R20 layout: [layer][slot], feature j = q + 8*slot)
    float syn[4][4], mem[4][4];
#pragma unroll
    for (int i = 0; i < 4; ++i)
#pragma unroll
        for (int s = 0; s < 4; ++s) { syn[i][s] = 0.0f; mem[i][s] = 0.0f; }

    const float* xp = x + (size_t)(b * kT * kN + n) * kF + q;

    float xv[4];
#pragma unroll
    for (int s = 0; s < 4; ++s) xv[s] = xp[8 * s];

    for (int tb = 0; tb < 12; ++tb) {
        // ======== 2 chain steps (byte-identical to R20) ====================
        for (int tt = 0; tt < 2; ++tt) {
            const int t = tb * 2 + tt;
            float xn[4] = {0.f, 0.f, 0.f, 0.f};
            if (t + 1 < kT) {
#pragma unroll
                for (int s = 0; s < 4; ++s) xn[s] = xp[(size_t)(t + 1) * kNF + 8 * s];
            }

            float hh[4];
#pragma unroll
            for (int s = 0; s < 4; ++s) hh[s] = xv[s];

#pragma unroll
            for (int i = 0; i < 4; ++i) {
                bool sp[4];
#pragma unroll
                for (int s = 0; s < 4; ++s) {
                    const float rst = ((mem[i][s] - th[i]) > 0.0f) ? 1.0f : 0.0f;
                    syn[i][s] = al[i] * syn[i][s] + hh[s];
                    mem[i][s] = be[i] * mem[i][s] + syn[i][s] - rst * th[i];
                    sp[s] = (mem[i][s] - th[i]) > 0.0f;
                }
                unsigned long long bal0 = __ballot(sp[0]);
                unsigned long long bal1 = __ballot(sp[1]);
                unsigned long long bal2 = __ballot(sp[2]);
                unsigned long long bal3 = __ballot(sp[3]);
                const unsigned f0 = (unsigned)((bal0 >> (r * 8)) & 0xFFull);
                const unsigned f1 = (unsigned)((bal1 >> (r * 8)) & 0xFFull);
                const unsigned f2 = (unsigned)((bal2 >> (r * 8)) & 0xFFull);
                const unsigned f3 = (unsigned)((bal3 >> (r * 8)) & 0xFFull);
                const unsigned m32 = f0 | (f1 << 8) | (f2 << 16) | (f3 << 24);

                if (i < 3) {
                    float4v vv[8];
#pragma unroll
                    for (int g = 0; g < 8; ++g) {
                        const unsigned nib = (m32 >> (4 * g)) & 15u;
                        vv[g] = *reinterpret_cast<const float4v*>(&lutQ[i][g][nib][q][0]);
                    }
#pragma unroll
                    for (int s = 0; s < 4; ++s)
                        hh[s] = ((vv[0][s] + vv[1][s]) + (vv[2][s] + vv[3][s]))
                              + ((vv[4][s] + vv[5][s]) + (vv[6][s] + vv[7][s]));
                } else if (q == 0) {
                    mlds[wid][tt][r] = m32;   // layer-3 mask, row r, parity tt
                }
            }

#pragma unroll
            for (int s = 0; s < 4; ++s) xv[s] = xn[s];
        }

        // ======== one MFMA tile: 8 rows x 2 t (R17 body; same-wave LDS) ====
        // tile row v: bn = base + (v&7), t = tb*2 + (v>>3)
        const unsigned m = mlds[wid][l16 >> 3][l16 & 7];
        short8v aspk;
#pragma unroll
        for (int e = 0; e < 8; ++e)
            aspk[e] = ((m >> (lg * 8 + e)) & 1u) ? (short)0x3F80 : (short)0;

        const short8v lf00 = wfrag[0][lane];
        const short8v lf01 = wfrag[1][lane];
        const short8v lf10 = wfrag[2][lane];
        const short8v lf11 = wfrag[3][lane];

        float4v t0 = {lbv[0], lbv[0], lbv[0], lbv[0]};
        float4v t1 = {lbv[1], lbv[1], lbv[1], lbv[1]};
        t0 = __builtin_amdgcn_mfma_f32_16x16x32_bf16(aspk, lf00, t0, 0, 0, 0);
        t0 = __builtin_amdgcn_mfma_f32_16x16x32_bf16(aspk, lf01, t0, 0, 0, 0);
        t1 = __builtin_amdgcn_mfma_f32_16x16x32_bf16(aspk, lf10, t1, 0, 0, 0);
        t1 = __builtin_amdgcn_mfma_f32_16x16x32_bf16(aspk, lf11, t1, 0, 0, 0);

#pragma unroll
        for (int rr = 0; rr < 4; ++rr) {
            gbuf[wid][lg * 4 + rr][l16]      = t0[rr];
            gbuf[wid][lg * 4 + rr][16 + l16] = t1[rr];
        }
        float tv[8];
        {
            const float* pt = &gbuf[wid][l16][lg * 8];
            *reinterpret_cast<float4*>(tv)     = *reinterpret_cast<const float4*>(pt);
            *reinterpret_cast<float4*>(tv + 4) = *reinterpret_cast<const float4*>(pt + 4);
        }
        short8v ahi, alo;
        cvt_hilo(tv, ahi, alo);

        float4v acc[4];
#pragma unroll
        for (int c0 = 0; c0 < 4; ++c0) {
            const short8v wf = wfrag[4 + c0][lane];
            float4v c = {b1v[c0], b1v[c0], b1v[c0], b1v[c0]};
            c = __builtin_amdgcn_mfma_f32_16x16x32_bf16(ahi, wf, c, 0, 0, 0);
            c = __builtin_amdgcn_mfma_f32_16x16x32_bf16(alo, wf, c, 0, 0, 0);
            acc[c0] = c;
        }

#pragma unroll
        for (int c0 = 0; c0 < 4; ++c0) {
#pragma unroll
            for (int rr = 0; rr < 4; ++rr) {
                float v = acc[c0][rr];
                v = (v > 0.0f) ? v : pa * v;
                gbuf[wid][lg * 4 + rr][c0 * 16 + l16] = v;
            }
        }

        float4v o[2];
#pragma unroll
        for (int c2 = 0; c2 < 2; ++c2)
            o[c2] = float4v{b2v[c2], b2v[c2], b2v[c2], b2v[c2]};
#pragma unroll
        for (int kb = 0; kb < 2; ++kb) {
            float gv[8];
            const float* pg = &gbuf[wid][l16][kb * 32 + lg * 8];
            *reinterpret_cast<float4*>(gv)     = *reinterpret_cast<const float4*>(pg);
            *reinterpret_cast<float4*>(gv + 4) = *reinterpret_cast<const float4*>(pg + 4);
            short8v ghi, glo;
            cvt_hilo(gv, ghi, glo);
#pragma unroll
            for (int c2 = 0; c2 < 2; ++c2) {
                const short8v wf = wfrag[8 + c2 * 2 + kb][lane];
                o[c2] = __builtin_amdgcn_mfma_f32_16x16x32_bf16(ghi, wf, o[c2], 0, 0, 0);
                o[c2] = __builtin_amdgcn_mfma_f32_16x16x32_bf16(glo, wf, o[c2], 0, 0, 0);
            }
        }

#pragma unroll
        for (int c2 = 0; c2 < 2; ++c2) {
#pragma unroll
            for (int rr = 0; rr < 4; ++rr) {
                const int v = lg * 4 + rr;
                const size_t orow =
                    ((size_t)(bq * kT + tb * 2 + (v >> 3)) * kN + (n0 + (v & 7))) * kF;
                out[orow + c2 * 16 + l16] = o[c2][rr];
            }
        }
    }
}
} // namespace

extern "C" void kernel_launch(void* const* d_in, const int* in_sizes, int n_in,
                              void* d_out, int out_size, void* d_ws, size_t ws_size,
                              hipStream_t stream) {
    const float* x        = (const float*)d_in[0];
    const float* alphas   = (const float*)d_in[1];
    const float* betas    = (const float*)d_in[2];
    const float* thrs     = (const float*)d_in[3];
    const float* chain_W  = (const float*)d_in[4];
    const float* chain_b  = (const float*)d_in[5];
    const float* lin_W    = (const float*)d_in[6];
    const float* lin_b    = (const float*)d_in[7];
    const float* W1       = (const float*)d_in[8];
    const float* b1       = (const float*)d_in[9];
    const float* prelu_a  = (const float*)d_in[10];
    const float* W2       = (const float*)d_in[11];
    const float* b2       = (const float*)d_in[12];
    float* out            = (float*)d_out;

    // 256 blocks * 8 waves * 8 rows = 16384 rows; fused chain+tile
    hipLaunchKernelGGL(snn_fused, dim3(256), dim3(512), 0, stream,
                       x, alphas, betas, thrs, chain_W, chain_b, lin_W, lin_b,
                       W1, b1, prelu_a, W2, b2, out);
}

// Round 22
// 47.278 us; speedup vs baseline: 1.6400x; 1.0611x over previous
//
#include <hip/hip_runtime.h>
#include <hip/hip_bf16.h>

// SNN "SynapticChain": B=4, T=24, N=4096, F=32, L=3 (+1 final synaptic layer).
// R22: R21 fused kernel with the tile phase swapped to R19's ALL-REGISTER
// transposed body (HW-refchecked in R19): layers computed with A=weights
// (kmap k-slot order, consistent on both operands -> contraction invariant),
// so each D output IS the next layer's B-fragment. gbuf DELETED -> R21's
// 3.7M bank-conflict cycles and ~30 LDS ops/tile gone; LDS 96.8->60.4KB.
// R19's weight-remat flaw fixed: all 12 fragments live in LDS wfrag (R21
// pattern), now stored in kmap order. Chain byte-identical to R20/R21 (LAW).
// Tile = mask b32 + 12 wfrag b128 + 20 MFMA + reg cvt/prelu + float4 stores.

namespace {
constexpr int kB = 4;
constexpr int kT = 24;
constexpr int kN = 4096;
constexpr int kF = 32;
constexpr int kNF = kN * kF;

typedef __attribute__((ext_vector_type(8))) short short8v;
typedef __attribute__((ext_vector_type(4))) float float4v;

__device__ __forceinline__ short bfc(float f) {
    return (short)__bfloat16_as_ushort(__float2bfloat16(f));
}
__device__ __forceinline__ float bfc_back(short s) {
    return __bfloat162float(__ushort_as_bfloat16((unsigned short)s));
}
__device__ __forceinline__ float uni(float v) {
    return __int_as_float(__builtin_amdgcn_readfirstlane(__float_as_int(v)));
}
__device__ __forceinline__ constexpr int kmap(int lg, int e) {
    return (e < 4) ? (lg * 4 + e) : (16 + lg * 4 + (e - 4));
}

__global__ __launch_bounds__(512, 2)
void snn_fused(const float* __restrict__ x,
               const float* __restrict__ alphas,
               const float* __restrict__ betas,
               const float* __restrict__ thrs,
               const float* __restrict__ chain_W,
               const float* __restrict__ chain_b,
               const float* __restrict__ lin_W,
               const float* __restrict__ lin_b,
               const float* __restrict__ W1,
               const float* __restrict__ b1,
               const float* __restrict__ prelu_a,
               const float* __restrict__ W2,
               const float* __restrict__ b2,
               float* __restrict__ out)
{
    const int tid  = threadIdx.x;
    const int lane = tid & 63;
    const int wid  = tid >> 6;              // 0..7
    const int r    = lane >> 3;             // chain: row within wave 0..7
    const int q    = lane & 7;              // chain: feature quad id 0..7
    const int l16  = lane & 15;             // mfma row/col
    const int lg   = lane >> 4;             // mfma 0..3

    const int base = (blockIdx.x * 8 + wid) * 8;    // wave's 8 bn-rows
    const int row  = base + r;
    const int b    = row >> 12;
    const int n    = row & (kN - 1);
    const int bq   = base >> 12;
    const int n0   = base & (kN - 1);

    __shared__ float    lutQ[3][8][16][8][4];  // 48 KB (chain, R20 layout)
    __shared__ short8v  wfrag[12][64];         // 12 KB  (tile weights, kmap)
    __shared__ unsigned mlds[8][2][8];         // 512 B  (masks [tt][r])

    // ---- LUT build: same arithmetic as R12/R17/R20, permuted layout
#pragma unroll
    for (int c = 0; c < 2; ++c) {
        const int idx = tid + c * 512;
        if (idx < 768) {
            const int mat = idx >> 8;
            const int g   = (idx >> 5) & 7;
            const int jj  = idx & 31;
            const float* wsrc = chain_W + ((mat * kF + jj) * kF + g * 4);
            const float4 w = *reinterpret_cast<const float4*>(wsrc);
            const float bias = (g == 0) ? chain_b[mat * kF + jj] : 0.0f;
            float s[16];
            s[0]  = 0.0f;
            s[1]  = w.x;         s[2]  = w.y;         s[3]  = w.x + w.y;
            s[4]  = w.z;         s[5]  = w.x + w.z;   s[6]  = w.y + w.z;
            s[7]  = s[3] + w.z;  s[8]  = w.w;         s[9]  = w.x + w.w;
            s[10] = w.y + w.w;   s[11] = s[3] + w.w;  s[12] = w.z + w.w;
            s[13] = s[5] + w.w;  s[14] = s[6] + w.w;  s[15] = s[7] + w.w;
#pragma unroll
            for (int nb = 0; nb < 16; ++nb)
                lutQ[mat][g][nb][jj & 7][jj >> 3] = s[nb] + bias;
        }
    }

    // ---- tile weight fragments -> LDS in KMAP order (A-side of transposed
    // layers). frag 0..3: lin_W (c=f>>1, split=f&1, double-split);
    // frag 4..7: W1 row-block; frag 8..11: W2 [oq][kb].
#pragma unroll
    for (int c = 0; c < 2; ++c) {
        const int idx = tid + c * 512;
        if (idx < 768) {
            const int f     = idx >> 6;
            const int lane2 = idx & 63;
            const int l16b  = lane2 & 15, lgb = lane2 >> 4;
            short8v fr;
            if (f < 4) {
                const int cc = f >> 1, sp = f & 1;
#pragma unroll
                for (int e = 0; e < 8; ++e) {
                    const float w  = lin_W[(cc * 16 + l16b) * 32 + kmap(lgb, e)];
                    const short s0 = bfc(w);
                    fr[e] = sp ? bfc(w - bfc_back(s0)) : s0;
                }
            } else if (f < 8) {
                const int c0 = f - 4;
#pragma unroll
                for (int e = 0; e < 8; ++e)
                    fr[e] = bfc(W1[(c0 * 16 + l16b) * 32 + kmap(lgb, e)]);
            } else {
                const int c2 = (f - 8) >> 1, kb = (f - 8) & 1;
#pragma unroll
                for (int e = 0; e < 8; ++e)
                    fr[e] = bfc(W2[(c2 * 16 + l16b) * 64 + kb * 32 + kmap(lgb, e)]);
            }
            wfrag[f][lane2] = fr;
        }
    }
    __syncthreads();

    // ---- uniform scalars -> SGPR (value-identical; VGPR relief)
    float al[4], be[4], th[4];
#pragma unroll
    for (int i = 0; i < 4; ++i) {
        al[i] = uni(fminf(fmaxf(alphas[i], 0.0f), 1.0f));
        be[i] = uni(fminf(fmaxf(betas[i],  0.0f), 1.0f));
        th[i] = uni(thrs[i]);
    }
    const float pa = uni(prelu_a[0]);

    // ---- chain state (R20 layout: [layer][slot], feature j = q + 8*slot)
    float syn[4][4], mem[4][4];
#pragma unroll
    for (int i = 0; i < 4; ++i)
#pragma unroll
        for (int s = 0; s < 4; ++s) { syn[i][s] = 0.0f; mem[i][s] = 0.0f; }

    const float* xp = x + (size_t)(b * kT * kN + n) * kF + q;

    float xv[4];
#pragma unroll
    for (int s = 0; s < 4; ++s) xv[s] = xp[8 * s];

    for (int tb = 0; tb < 12; ++tb) {
        // ======== 2 chain steps (byte-identical to R20/R21) ================
        for (int tt = 0; tt < 2; ++tt) {
            const int t = tb * 2 + tt;
            float xn[4] = {0.f, 0.f, 0.f, 0.f};
            if (t + 1 < kT) {
#pragma unroll
                for (int s = 0; s < 4; ++s) xn[s] = xp[(size_t)(t + 1) * kNF + 8 * s];
            }

            float hh[4];
#pragma unroll
            for (int s = 0; s < 4; ++s) hh[s] = xv[s];

#pragma unroll
            for (int i = 0; i < 4; ++i) {
                bool sp[4];
#pragma unroll
                for (int s = 0; s < 4; ++s) {
                    const float rst = ((mem[i][s] - th[i]) > 0.0f) ? 1.0f : 0.0f;
                    syn[i][s] = al[i] * syn[i][s] + hh[s];
                    mem[i][s] = be[i] * mem[i][s] + syn[i][s] - rst * th[i];
                    sp[s] = (mem[i][s] - th[i]) > 0.0f;
                }
                unsigned long long bal0 = __ballot(sp[0]);
                unsigned long long bal1 = __ballot(sp[1]);
                unsigned long long bal2 = __ballot(sp[2]);
                unsigned long long bal3 = __ballot(sp[3]);
                const unsigned f0 = (unsigned)((bal0 >> (r * 8)) & 0xFFull);
                const unsigned f1 = (unsigned)((bal1 >> (r * 8)) & 0xFFull);
                const unsigned f2 = (unsigned)((bal2 >> (r * 8)) & 0xFFull);
                const unsigned f3 = (unsigned)((bal3 >> (r * 8)) & 0xFFull);
                const unsigned m32 = f0 | (f1 << 8) | (f2 << 16) | (f3 << 24);

                if (i < 3) {
                    float4v vv[8];
#pragma unroll
                    for (int g = 0; g < 8; ++g) {
                        const unsigned nib = (m32 >> (4 * g)) & 15u;
                        vv[g] = *reinterpret_cast<const float4v*>(&lutQ[i][g][nib][q][0]);
                    }
#pragma unroll
                    for (int s = 0; s < 4; ++s)
                        hh[s] = ((vv[0][s] + vv[1][s]) + (vv[2][s] + vv[3][s]))
                              + ((vv[4][s] + vv[5][s]) + (vv[6][s] + vv[7][s]));
                } else if (q == 0) {
                    mlds[wid][tt][r] = m32;   // layer-3 mask, row r, parity tt
                }
            }

#pragma unroll
            for (int s = 0; s < 4; ++s) xv[s] = xn[s];
        }

        // ======== all-register tile (R19 body): 8 rows x 2 t ==============
        // tile row = l16: bn = base + (l16&7), t = tb*2 + (l16>>3)
        const unsigned m = mlds[wid][l16 >> 3][l16 & 7];
        short8v aspk;
#pragma unroll
        for (int e = 0; e < 8; ++e)
            aspk[e] = ((m >> kmap(lg, e)) & 1u) ? (short)0x3F80 : (short)0;

        // lin_out^T: A = lin_W frags (double-split), B = spikes
        const float4 lb0 = *reinterpret_cast<const float4*>(lin_b + lg * 4);
        const float4 lb1 = *reinterpret_cast<const float4*>(lin_b + 16 + lg * 4);
        float4v t0 = {lb0.x, lb0.y, lb0.z, lb0.w};
        float4v t1 = {lb1.x, lb1.y, lb1.z, lb1.w};
        t0 = __builtin_amdgcn_mfma_f32_16x16x32_bf16(wfrag[0][lane], aspk, t0, 0, 0, 0);
        t0 = __builtin_amdgcn_mfma_f32_16x16x32_bf16(wfrag[1][lane], aspk, t0, 0, 0, 0);
        t1 = __builtin_amdgcn_mfma_f32_16x16x32_bf16(wfrag[2][lane], aspk, t1, 0, 0, 0);
        t1 = __builtin_amdgcn_mfma_f32_16x16x32_bf16(wfrag[3][lane], aspk, t1, 0, 0, 0);

        // T -> hi/lo B-fragments (slot e<4 from t0[e], e>=4 from t1[e-4])
        short8v thi, tlo;
#pragma unroll
        for (int e = 0; e < 4; ++e) {
            const short h0 = bfc(t0[e]);
            thi[e] = h0; tlo[e] = bfc(t0[e] - bfc_back(h0));
            const short h1 = bfc(t1[e]);
            thi[4 + e] = h1; tlo[4 + e] = bfc(t1[e] - bfc_back(h1));
        }

        // layer1^T + prelu: g[q4*4+r] = G[l16][q4*16+lg*4+r]
        float g[16];
#pragma unroll
        for (int q4 = 0; q4 < 4; ++q4) {
            const float4 b14 = *reinterpret_cast<const float4*>(b1 + q4 * 16 + lg * 4);
            float4v c = {b14.x, b14.y, b14.z, b14.w};
            const short8v wf = wfrag[4 + q4][lane];
            c = __builtin_amdgcn_mfma_f32_16x16x32_bf16(wf, thi, c, 0, 0, 0);
            c = __builtin_amdgcn_mfma_f32_16x16x32_bf16(wf, tlo, c, 0, 0, 0);
#pragma unroll
            for (int rr = 0; rr < 4; ++rr) {
                const float v = c[rr];
                g[q4 * 4 + rr] = (v > 0.0f) ? v : pa * v;
            }
        }

        // G -> hi/lo B-fragments per kb (slot e <-> g[kb*8+e])
        short8v gh[2], gl[2];
#pragma unroll
        for (int kb = 0; kb < 2; ++kb)
#pragma unroll
            for (int e = 0; e < 8; ++e) {
                const float v = g[kb * 8 + e];
                const short h0 = bfc(v);
                gh[kb][e] = h0;
                gl[kb][e] = bfc(v - bfc_back(h0));
            }

        // layer2^T + store: lane holds out[l16][oq*16+lg*4+r] -> float4
        const size_t orow =
            ((size_t)(bq * kT + tb * 2 + (l16 >> 3)) * kN + (n0 + (l16 & 7))) * kF;
#pragma unroll
        for (int oq = 0; oq < 2; ++oq) {
            const float4 b24 = *reinterpret_cast<const float4*>(b2 + oq * 16 + lg * 4);
            float4v o = {b24.x, b24.y, b24.z, b24.w};
            o = __builtin_amdgcn_mfma_f32_16x16x32_bf16(wfrag[8 + oq * 2 + 0][lane], gh[0], o, 0, 0, 0);
            o = __builtin_amdgcn_mfma_f32_16x16x32_bf16(wfrag[8 + oq * 2 + 0][lane], gl[0], o, 0, 0, 0);
            o = __builtin_amdgcn_mfma_f32_16x16x32_bf16(wfrag[8 + oq * 2 + 1][lane], gh[1], o, 0, 0, 0);
            o = __builtin_amdgcn_mfma_f32_16x16x32_bf16(wfrag[8 + oq * 2 + 1][lane], gl[1], o, 0, 0, 0);
            float4 st = {o[0], o[1], o[2], o[3]};
            *reinterpret_cast<float4*>(out + orow + oq * 16 + lg * 4) = st;
        }
    }
}
} // namespace

extern "C" void kernel_launch(void* const* d_in, const int* in_sizes, int n_in,
                              void* d_out, int out_size, void* d_ws, size_t ws_size,
                              hipStream_t stream) {
    const float* x        = (const float*)d_in[0];
    const float* alphas   = (const float*)d_in[1];
    const float* betas    = (const float*)d_in[2];
    const float* thrs     = (const float*)d_in[3];
    const float* chain_W  = (const float*)d_in[4];
    const float* chain_b  = (const float*)d_in[5];
    const float* lin_W    = (const float*)d_in[6];
    const float* lin_b    = (const float*)d_in[7];
    const float* W1       = (const float*)d_in[8];
    const float* b1       = (const float*)d_in[9];
    const float* prelu_a  = (const float*)d_in[10];
    const float* W2       = (const float*)d_in[11];
    const float* b2       = (const float*)d_in[12];
    float* out            = (float*)d_out;

    // 256 blocks * 8 waves * 8 rows = 16384 rows; fused chain + all-reg tile
    hipLaunchKernelGGL(snn_fused, dim3(256), dim3(512), 0, stream,
                       x, alphas, betas, thrs, chain_W, chain_b, lin_W, lin_b,
                       W1, b1, prelu_a, W2, b2, out);
}